// Round 5
// baseline (464.813 us; speedup 1.0000x reference)
//
#include <hip/hip_runtime.h>

// Sliding-window attention, MI355X/gfx950. Round 5.
// RESOLVED: inputs fp32, output fp32 (R0/R1/R2/R3/R4 failure signatures
// over-determine this; R2===R3 bit-match proves the MFMA/flash math correct).
// Pipeline: convert x->bf16, convert+transpose weights -> bf16;
// m97 MFMA GEMM (qkv, bf16 out) -> V transpose -> flash windowed attention
// -> m97 GEMM with FP32 epilogue into d_out. ws usage: 200 MB.

typedef unsigned short u16;
typedef unsigned int u32;
typedef __attribute__((ext_vector_type(8))) short bf16x8;   // 8 x bf16 (4 VGPRs)
typedef __attribute__((ext_vector_type(4))) float f32x4;

__device__ __forceinline__ float bf2f(u16 v) {
  union { u32 u; float f; } t; t.u = ((u32)v) << 16; return t.f;
}
__device__ __forceinline__ u16 f2bf(float f) {
  union { float f; u32 u; } t; t.f = f;
  u32 u = t.u + 0x7fffu + ((t.u >> 16) & 1u);   // RNE
  return (u16)(u >> 16);
}
__device__ __forceinline__ void g2lds16(const void* g, void* l) {
  __builtin_amdgcn_global_load_lds((const __attribute__((address_space(1))) void*)g,
                                   (__attribute__((address_space(3))) void*)l,
                                   16, 0, 0);
}

// ---------------------------------------------------------------------------
// x [16384][1024] fp32 -> bf16, flat
// ---------------------------------------------------------------------------
__global__ __launch_bounds__(256) void canon_x(
    const float* __restrict__ xf, u16* __restrict__ xb) {
  size_t i = ((size_t)blockIdx.x * 256 + threadIdx.x) * 8;
  float4 a = *(const float4*)(xf + i);
  float4 b = *(const float4*)(xf + i + 4);
  u16 o[8] = { f2bf(a.x), f2bf(a.y), f2bf(a.z), f2bf(a.w),
               f2bf(b.x), f2bf(b.y), f2bf(b.z), f2bf(b.w) };
  *(bf16x8*)(xb + i) = *(bf16x8*)o;
}

// ---------------------------------------------------------------------------
// Weight transpose+convert: in [R][C] fp32 -> out [C][R] bf16
// ---------------------------------------------------------------------------
__global__ __launch_bounds__(256) void transpose_w(
    const float* __restrict__ in, u16* __restrict__ out, int R, int C) {
  __shared__ u16 tile[32][33];
  int c0 = blockIdx.x * 32, r0 = blockIdx.y * 32;
  int tx = threadIdx.x & 31, ty = threadIdx.x >> 5;
#pragma unroll
  for (int i = 0; i < 32; i += 8)
    tile[ty + i][tx] = f2bf(in[(size_t)(r0 + ty + i) * C + c0 + tx]);
  __syncthreads();
#pragma unroll
  for (int i = 0; i < 32; i += 8)
    out[(size_t)(c0 + ty + i) * R + r0 + tx] = tile[tx][ty + i];
}

// ---------------------------------------------------------------------------
// V part of qkv [16384][3072] -> Vt [bh=512][d=64][t=512]   (bf16)
// ---------------------------------------------------------------------------
__global__ __launch_bounds__(256) void transpose_v(
    const u16* __restrict__ qkv, u16* __restrict__ vt) {
  __shared__ u16 tile[32][33];
  int bh = blockIdx.z, bn = bh >> 4, h = bh & 15;
  int t0 = blockIdx.x * 32, d0 = blockIdx.y * 32;
  int tx = threadIdx.x & 31, ty = threadIdx.x >> 5;
  const u16* src = qkv + (size_t)(bn * 512) * 3072 + 2048 + h * 64;
#pragma unroll
  for (int i = 0; i < 32; i += 8)
    tile[ty + i][tx] = src[(size_t)(t0 + ty + i) * 3072 + d0 + tx];
  __syncthreads();
  u16* dst = vt + ((size_t)bh * 64 + d0) * 512 + t0;
#pragma unroll
  for (int i = 0; i < 32; i += 8)
    dst[(size_t)(ty + i) * 512 + tx] = tile[tx][ty + i];
}

// ---------------------------------------------------------------------------
// C[M,N] = A[M,K](bf16) * Bt[N,K]^T(bf16) + bias[N](fp32); OutT u16|float.
// m97 structure: 128x128 tile, BK=32, 2x2 waves of 64x64, global_load_lds w=16.
// ---------------------------------------------------------------------------
template <typename OutT>
__global__ __launch_bounds__(256, 2) void gemm_bt_bias(
    const u16* __restrict__ A, const u16* __restrict__ Bt,
    const float* __restrict__ bias, OutT* __restrict__ C,
    int M, int N, int K) {
  __shared__ __align__(16) u16 As[128 * 32];
  __shared__ __align__(16) u16 Bs[128 * 32];
  const int tid = threadIdx.x;
  const int wave = tid >> 6, lane = tid & 63;
  const int quad = lane >> 4, l16 = lane & 15;
  const int m0 = blockIdx.y * 128, n0 = blockIdx.x * 128;
  const int wm = (wave >> 1) * 64, wn = (wave & 1) * 64;

  f32x4 acc[4][4] = {};

  int e0 = (wave * 512) + lane * 8;   // chunk 0 element offset in 128x32 tile
  int e1 = 2048 + e0;                 // chunk 1
  int rA0 = e0 >> 5, cA0 = e0 & 31;
  int rA1 = e1 >> 5, cA1 = e1 & 31;
  const u16* ga0 = A + (size_t)(m0 + rA0) * K + cA0;
  const u16* ga1 = A + (size_t)(m0 + rA1) * K + cA1;
  const u16* gb0 = Bt + (size_t)(n0 + rA0) * K + cA0;
  const u16* gb1 = Bt + (size_t)(n0 + rA1) * K + cA1;
  u16* As0 = As + (size_t)wave * 512;
  u16* As1 = As0 + 2048;
  u16* Bs0 = Bs + (size_t)wave * 512;
  u16* Bs1 = Bs0 + 2048;

  for (int k0 = 0; k0 < K; k0 += 32) {
    g2lds16(ga0 + k0, As0);
    g2lds16(ga1 + k0, As1);
    g2lds16(gb0 + k0, Bs0);
    g2lds16(gb1 + k0, Bs1);
    __syncthreads();
    bf16x8 a[4], b[4];
#pragma unroll
    for (int mi = 0; mi < 4; ++mi)
      a[mi] = *(const bf16x8*)(As + (wm + mi * 16 + l16) * 32 + quad * 8);
#pragma unroll
    for (int ni = 0; ni < 4; ++ni)
      b[ni] = *(const bf16x8*)(Bs + (wn + ni * 16 + l16) * 32 + quad * 8);
#pragma unroll
    for (int mi = 0; mi < 4; ++mi)
#pragma unroll
      for (int ni = 0; ni < 4; ++ni)
        acc[mi][ni] = __builtin_amdgcn_mfma_f32_16x16x32_bf16(a[mi], b[ni], acc[mi][ni], 0, 0, 0);
    __syncthreads();
  }

  // epilogue: C/D layout col=l16, row=quad*4+reg
#pragma unroll
  for (int ni = 0; ni < 4; ++ni) {
    int col = n0 + wn + ni * 16 + l16;
    float bv = bias[col];
#pragma unroll
    for (int mi = 0; mi < 4; ++mi) {
      int row = m0 + wm + mi * 16 + quad * 4;
#pragma unroll
      for (int r = 0; r < 4; ++r) {
        float v = acc[mi][ni][r] + bv;
        if constexpr (sizeof(OutT) == 2)
          C[(size_t)(row + r) * N + col] = f2bf(v);
        else
          C[(size_t)(row + r) * N + col] = v;
      }
    }
  }
}

// ---------------------------------------------------------------------------
// Windowed causal flash attention. Grid (qt=4, h=16, bn=32), 256 threads.
// Vector-load staging into XOR-swizzled LDS; online softmax; P via LDS.
// LDS 80KB -> 2 blocks/CU. Numerics cross-validated against naive (R2===R3).
// ---------------------------------------------------------------------------
__global__ __launch_bounds__(256, 2) void attn_win(
    const u16* __restrict__ qkv, const u16* __restrict__ vt,
    u16* __restrict__ attn) {
  __shared__ __align__(16) u16 Qs[128 * 64];
  __shared__ __align__(16) u16 Ks[128 * 64];
  __shared__ __align__(16) u16 Vs[64 * 128];
  __shared__ __align__(16) u16 Ps[4][32 * 128];

  const int qt = blockIdx.x, h = blockIdx.y, bn = blockIdx.z;
  const int bh = bn * 16 + h;
  const int tid = threadIdx.x;
  const int wave = tid >> 6, lane = tid & 63;
  const int quad = lane >> 4, l16 = lane & 15;
  const int t0 = bn * 512 + qt * 128;

  // ---- stage Q [128 rows][8 chunks], phys chunk = c ^ (row&7) ----
#pragma unroll
  for (int it = 0; it < 4; ++it) {
    int i = it * 256 + tid;
    int row = i >> 3, c = i & 7;
    bf16x8 v = *(const bf16x8*)(qkv + (size_t)(t0 + row) * 3072 + h * 64 + c * 8);
    *(bf16x8*)(Qs + row * 64 + ((c ^ (row & 7)) * 8)) = v;
  }

  float mrun[2][4], lrun[2][4];
  f32x4 o[2][4] = {};
#pragma unroll
  for (int mi = 0; mi < 2; ++mi)
#pragma unroll
    for (int r = 0; r < 4; ++r) { mrun[mi][r] = -1e30f; lrun[mi][r] = 0.f; }

  const float cexp = 0.18033688011112042f;  // (1/sqrt(64)) * log2(e)

  for (int j = 0; j <= qt; ++j) {
    int tk = bn * 512 + j * 128;
#pragma unroll
    for (int it = 0; it < 4; ++it) {
      int i = it * 256 + tid;
      int rk = i >> 3, ck = i & 7;
      bf16x8 kv = *(const bf16x8*)(qkv + (size_t)(tk + rk) * 3072 + 1024 + h * 64 + ck * 8);
      *(bf16x8*)(Ks + rk * 64 + ((ck ^ (rk & 7)) * 8)) = kv;
      int rv = i >> 4, cv = i & 15;
      bf16x8 vv = *(const bf16x8*)(vt + ((size_t)bh * 64 + rv) * 512 + j * 128 + cv * 8);
      *(bf16x8*)(Vs + rv * 128 + ((cv ^ (rv & 15)) * 8)) = vv;
    }
    __syncthreads();

    // ---- S = Q K^T (this wave: rows [wave*32, +32)) ----
    f32x4 s[2][8] = {};
#pragma unroll
    for (int ks = 0; ks < 2; ++ks) {
      bf16x8 aq[2];
#pragma unroll
      for (int mi = 0; mi < 2; ++mi) {
        int m = wave * 32 + mi * 16 + l16;
        aq[mi] = *(const bf16x8*)(Qs + m * 64 + (((ks * 4 + quad) ^ (m & 7)) * 8));
      }
#pragma unroll
      for (int ni = 0; ni < 8; ++ni) {
        int n = ni * 16 + l16;
        bf16x8 bk = *(const bf16x8*)(Ks + n * 64 + (((ks * 4 + quad) ^ (n & 7)) * 8));
        s[0][ni] = __builtin_amdgcn_mfma_f32_16x16x32_bf16(aq[0], bk, s[0][ni], 0, 0, 0);
        s[1][ni] = __builtin_amdgcn_mfma_f32_16x16x32_bf16(aq[1], bk, s[1][ni], 0, 0, 0);
      }
    }

    // ---- online softmax (C layout: col=l16, row=quad*4+r) ----
    const bool diag = (j == qt);
#pragma unroll
    for (int mi = 0; mi < 2; ++mi) {
#pragma unroll
      for (int r = 0; r < 4; ++r) {
        int m = wave * 32 + mi * 16 + quad * 4 + r;
        float rmax = -1e30f;
#pragma unroll
        for (int ni = 0; ni < 8; ++ni) {
          float v = s[mi][ni][r] * cexp;
          if (diag && (ni * 16 + l16 > m)) v = -1e30f;
          s[mi][ni][r] = v;
          rmax = fmaxf(rmax, v);
        }
        rmax = fmaxf(rmax, __shfl_xor(rmax, 1));
        rmax = fmaxf(rmax, __shfl_xor(rmax, 2));
        rmax = fmaxf(rmax, __shfl_xor(rmax, 4));
        rmax = fmaxf(rmax, __shfl_xor(rmax, 8));
        float mnew = fmaxf(mrun[mi][r], rmax);
        float alpha = exp2f(mrun[mi][r] - mnew);
        mrun[mi][r] = mnew;
        float rsum = 0.f;
#pragma unroll
        for (int ni = 0; ni < 8; ++ni) {
          float pv = exp2f(s[mi][ni][r] - mnew);
          s[mi][ni][r] = pv;
          rsum += pv;
        }
        rsum += __shfl_xor(rsum, 1);
        rsum += __shfl_xor(rsum, 2);
        rsum += __shfl_xor(rsum, 4);
        rsum += __shfl_xor(rsum, 8);
        lrun[mi][r] = lrun[mi][r] * alpha + rsum;
#pragma unroll
        for (int di = 0; di < 4; ++di) o[mi][di][r] *= alpha;
      }
    }

    // ---- P (C layout) -> wave-private LDS in A layout, swz ^(row&15) ----
    u16* pw = &Ps[wave][0];
#pragma unroll
    for (int mi = 0; mi < 2; ++mi)
#pragma unroll
      for (int ni = 0; ni < 8; ++ni)
#pragma unroll
        for (int r = 0; r < 4; ++r) {
          int row = mi * 16 + quad * 4 + r;
          int col = ni * 16 + l16;
          int phys = (col >> 3) ^ (row & 15);
          pw[row * 128 + phys * 8 + (col & 7)] = f2bf(s[mi][ni][r]);
        }
    __syncthreads();

    // ---- O += P V ----
#pragma unroll
    for (int ks = 0; ks < 4; ++ks) {
      bf16x8 ap[2];
#pragma unroll
      for (int mi = 0; mi < 2; ++mi) {
        int row = mi * 16 + l16;
        ap[mi] = *(const bf16x8*)(pw + row * 128 + (((ks * 4 + quad) ^ (row & 15)) * 8));
      }
#pragma unroll
      for (int di = 0; di < 4; ++di) {
        int n = di * 16 + l16;
        bf16x8 bv = *(const bf16x8*)(Vs + n * 128 + (((ks * 4 + quad) ^ (n & 15)) * 8));
        o[0][di] = __builtin_amdgcn_mfma_f32_16x16x32_bf16(ap[0], bv, o[0][di], 0, 0, 0);
        o[1][di] = __builtin_amdgcn_mfma_f32_16x16x32_bf16(ap[1], bv, o[1][di], 0, 0, 0);
      }
    }
    __syncthreads();
  }

  // ---- epilogue: O / l -> attn [token][h*64+d] (bf16) ----
#pragma unroll
  for (int mi = 0; mi < 2; ++mi)
#pragma unroll
    for (int r = 0; r < 4; ++r) {
      float inv = 1.0f / lrun[mi][r];
      int trow = t0 + wave * 32 + mi * 16 + quad * 4 + r;
#pragma unroll
      for (int di = 0; di < 4; ++di)
        attn[(size_t)trow * 1024 + h * 64 + di * 16 + l16] = f2bf(o[mi][di][r] * inv);
    }
}

// ---------------------------------------------------------------------------
extern "C" void kernel_launch(void* const* d_in, const int* in_sizes, int n_in,
                              void* d_out, int out_size, void* d_ws, size_t ws_size,
                              hipStream_t stream) {
  (void)in_sizes; (void)n_in; (void)out_size; (void)ws_size;
  const float* x     = (const float*)d_in[0];   // [16384][1024] fp32
  const float* w_qkv = (const float*)d_in[1];   // [1024][3072] fp32
  const float* b_qkv = (const float*)d_in[2];   // [3072] fp32
  const float* w_o   = (const float*)d_in[3];   // [1024][1024] fp32
  const float* b_o   = (const float*)d_in[4];   // [1024] fp32
  float* out = (float*)d_out;                   // [16384][1024] fp32

  char* ws = (char*)d_ws;
  u16* qkv   = (u16*)(ws + 0);            // 96 MB
  u16* vtb   = (u16*)(ws + 100663296);    // 32 MB
  u16* attnb = (u16*)(ws + 134217728);    // 32 MB
  u16* xb    = (u16*)(ws + 167772160);    // 32 MB
  u16* wqkvT = (u16*)(ws + 201326592);    // 6 MB
  u16* woT   = (u16*)(ws + 207618048);    // 2 MB  (total 200 MB)

  canon_x<<<8192, 256, 0, stream>>>(x, xb);
  transpose_w<<<dim3(96, 32), 256, 0, stream>>>(w_qkv, wqkvT, 1024, 3072);
  transpose_w<<<dim3(32, 32), 256, 0, stream>>>(w_o, woT, 1024, 1024);

  gemm_bt_bias<u16><<<dim3(24, 128), 256, 0, stream>>>(
      xb, wqkvT, b_qkv, qkv, 16384, 3072, 1024);
  transpose_v<<<dim3(16, 2, 512), 256, 0, stream>>>(qkv, vtb);
  attn_win<<<dim3(4, 16, 32), 256, 0, stream>>>(qkv, vtb, attnb);
  gemm_bt_bias<float><<<dim3(8, 128), 256, 0, stream>>>(
      attnb, woT, b_o, out, 16384, 1024, 1024);
}